// Round 4
// baseline (578.736 us; speedup 1.0000x reference)
//
#include <hip/hip_runtime.h>
#include <hip/hip_bf16.h>
#include <float.h>

// z: (64, 256, 32, 32) fp32 ; emb: (1024, 256) fp32
// M = 65536 pixels, D = 256, K = 1024 codes
// out: [z_q (16777216 f)] [indices as float (65536)] [vq_loss (1)]
#define OUT_IDX_OFF 16777216
#define OUT_LOSS_OFF 16842752
// scratch inside d_out's z_q region (overwritten by k_out at the end):
// A2 bf16: floats [0, 8388608)
// cand pairs (s, k) float2: floats [8388608, 12582912)   65536 rows x 32 slots
// gmin (int-punned f32):    floats [12582912, 13107200)
// gcnt (int):               floats [13107200, 13631488)
#define CAND_OFF 8388608
#define GMIN_OFF 12582912
#define GCNT_OFF 13107200
#define NSLOT 32
#define DELTA 2.0e-3f

typedef __attribute__((ext_vector_type(8))) short short8;
typedef __attribute__((ext_vector_type(4))) float f32x4;

static __device__ __forceinline__ unsigned short f2bf(float f) {
  union { __hip_bfloat16 h; unsigned short u; } cv;
  cv.h = __float2bfloat16(f);
  return cv.u;
}

// ---------------------------------------------------------------------------
// P1: emb -> E2 bf16 [1024 codes][256 d] + exact cws (proven r1-r3).
// ---------------------------------------------------------------------------
__global__ __launch_bounds__(256) void k_prep(const float* __restrict__ emb,
                                              unsigned short* __restrict__ E2,
                                              float* __restrict__ cws) {
  const int k = blockIdx.x, d = threadIdx.x;
  const float v = emb[k * 256 + d];
  __shared__ float red[256];
  __shared__ unsigned short row[256];
  row[d] = f2bf(v);
  red[d] = v * v;
  __syncthreads();
  for (int s = 128; s > 0; s >>= 1) {
    if (d < s) red[d] += red[d + s];
    __syncthreads();
  }
  if (d == 0) cws[k] = red[0];
  if (d < 32) ((short8*)&E2[k * 256])[d] = ((short8*)row)[d];
}

// ---------------------------------------------------------------------------
// P2: z (NCHW) -> A2 bf16 [pixel][256] via LDS transpose (proven r3).
// ---------------------------------------------------------------------------
__global__ __launch_bounds__(256) void k_cvt(const float* __restrict__ z,
                                             unsigned short* __restrict__ A2) {
  __shared__ float tile[32][258];
  const int t = threadIdx.x;
  const int p0 = blockIdx.x << 5;  // 32 pixels
  const int n = p0 >> 10, hw0 = p0 & 1023;
  const float* zb = z + (size_t)n * 262144 + hw0 + (t & 31);
  const int dh = t >> 5;  // 0..7
#pragma unroll
  for (int dd = 0; dd < 32; ++dd) {
    const int d = dd * 8 + dh;
    tile[t & 31][d] = zb[(size_t)d * 1024];
  }
  __syncthreads();
  const int p = t >> 3;            // pixel 0..31
  const int c0 = (t & 7) * 4;      // short8 chunk base
  unsigned short tmp[32];
#pragma unroll
  for (int j = 0; j < 32; ++j) tmp[j] = f2bf(tile[p][(t & 7) * 32 + j]);
  short8* dst = (short8*)&A2[(size_t)(p0 + p) * 256];
#pragma unroll
  for (int j = 0; j < 4; ++j) dst[c0 + j] = ((short8*)tmp)[j];
}

// ---------------------------------------------------------------------------
// k_a: exact numpy-pairwise ||x||^2 (proven, unchanged).
// ---------------------------------------------------------------------------
__global__ __launch_bounds__(256) void k_a(const float* __restrict__ z,
                                           float* __restrict__ aws) {
#pragma clang fp contract(off)
  const int t = threadIdx.x;
  const int r = (blockIdx.x << 7) + (t & 127);
  const int h = t >> 7;
  const int n = r >> 10;
  const int hw = r & 1023;
  const float* zp = z + (size_t)n * 262144 + hw + (size_t)h * 131072;
  float acc[8];
#pragma unroll
  for (int j = 0; j < 8; ++j) {
    const float x = zp[(size_t)j * 1024];
    acc[j] = x * x;
  }
  for (int g = 1; g < 16; ++g) {
#pragma unroll
    for (int j = 0; j < 8; ++j) {
      const float x = zp[(size_t)(g * 8 + j) * 1024];
      const float p = x * x;
      acc[j] = acc[j] + p;
    }
  }
  const float s = ((acc[0] + acc[1]) + (acc[2] + acc[3])) +
                  ((acc[4] + acc[5]) + (acc[6] + acc[7]));
  __shared__ float red[256];
  red[t] = s;
  __syncthreads();
  if (t < 128) aws[(blockIdx.x << 7) + t] = red[t] + red[t + 128];
}

// ---------------------------------------------------------------------------
// k_gemm2: occupancy-first MFMA prefilter. Block = 128 pixels x 128 codes,
// grid = 512 rowblocks x 8 codechunks. BK=64 streamed, XOR-swizzled LDS
// (chunk ^ (row&7), row stride 64 shorts) -> conflict-free b128 reads/writes.
// LDS ~35 KB, no prefetch regs -> rely on 8-12 waves/CU for latency hiding
// (r3 lesson: 1 wave/SIMD starves both pipes).
// Per-block epilogue: chunk-local per-row min -> atomicMin(gmin) (int-punned,
// scores>0) + candidate append (s <= chunkmin+DELTA, superset of global set).
// ---------------------------------------------------------------------------
__global__ __launch_bounds__(256, 1) void k_gemm2(
    const unsigned short* __restrict__ A2, const unsigned short* __restrict__ E2,
    const float* __restrict__ cws, const float* __restrict__ aws,
    int* __restrict__ gmin, int* __restrict__ gcnt,
    float2* __restrict__ gcand) {
  __shared__ __align__(16) unsigned short As[128 * 64];
  __shared__ __align__(16) unsigned short Bs[128 * 64];
  __shared__ float a_l[128], c_l[128], rmkt[256], bmin[128];

  const int t = threadIdx.x;
  const int lane = t & 63, wave = t >> 6;
  const int wr = wave >> 1, wc = wave & 1;
  const int quad = lane >> 4, l15 = lane & 15;
  const int rb = blockIdx.x >> 3, ck = blockIdx.x & 7;
  const int r0 = rb << 7, k0 = ck << 7;

  if (t < 128) {
    a_l[t] = aws[r0 + t];
    c_l[t] = cws[k0 + t];
  }

  const short8* gA8 = (const short8*)A2;
  const short8* gE8 = (const short8*)E2;
  const int srow = t >> 3;                          // 0..31
  const int sch = t & 7;                            // 0..7
  const int swst = (sch ^ (srow & 7)) << 3;         // swizzled short offset
  const int swa = l15 & 7;                          // frag-read swizzle mask

  f32x4 acc[4][4];
#pragma unroll
  for (int a = 0; a < 4; ++a)
#pragma unroll
    for (int b = 0; b < 4; ++b) acc[a][b] = (f32x4)(0.0f);

  for (int kt = 0; kt < 4; ++kt) {
    if (kt) __syncthreads();  // previous compute done before overwrite
    short8 va[4], vb[4];
#pragma unroll
    for (int s = 0; s < 4; ++s) {
      const int row = s * 32 + srow;
      va[s] = gA8[(size_t)(r0 + row) * 32 + kt * 8 + sch];
      vb[s] = gE8[(size_t)(k0 + row) * 32 + kt * 8 + sch];
    }
#pragma unroll
    for (int s = 0; s < 4; ++s) {
      const int row = s * 32 + srow;
      *(short8*)&As[row * 64 + swst] = va[s];
      *(short8*)&Bs[row * 64 + swst] = vb[s];
    }
    __syncthreads();
#pragma unroll
    for (int ks = 0; ks < 2; ++ks) {
      short8 af[4], bf[4];
#pragma unroll
      for (int tr = 0; tr < 4; ++tr)
        af[tr] = *(const short8*)&As[(wr * 64 + tr * 16 + l15) * 64 +
                                     (((ks * 4 + quad) ^ swa) << 3)];
#pragma unroll
      for (int tc = 0; tc < 4; ++tc)
        bf[tc] = *(const short8*)&Bs[(wc * 64 + tc * 16 + l15) * 64 +
                                     (((ks * 4 + quad) ^ swa) << 3)];
#pragma unroll
      for (int tr = 0; tr < 4; ++tr)
#pragma unroll
        for (int tc = 0; tc < 4; ++tc)
          acc[tr][tc] = __builtin_amdgcn_mfma_f32_16x16x32_bf16(
              af[tr], bf[tc], acc[tr][tc], 0, 0, 0);
    }
  }

  // epilogue pass 1: chunk-local per-row min (s_full = a + c - 2*dot > 0)
#pragma unroll
  for (int tr = 0; tr < 4; ++tr)
#pragma unroll
    for (int rg = 0; rg < 4; ++rg) {
      const int rloc = wr * 64 + tr * 16 + quad * 4 + rg;
      const float av = a_l[rloc];
      float mn = FLT_MAX;
#pragma unroll
      for (int tc = 0; tc < 4; ++tc) {
        const int cloc = wc * 64 + tc * 16 + l15;
        const float s = av + fmaf(-2.0f, acc[tr][tc][rg], c_l[cloc]);
        mn = fminf(mn, s);
      }
      mn = fminf(mn, __shfl_xor(mn, 1));
      mn = fminf(mn, __shfl_xor(mn, 2));
      mn = fminf(mn, __shfl_xor(mn, 4));
      mn = fminf(mn, __shfl_xor(mn, 8));
      if (l15 == 0) rmkt[rloc * 2 + wc] = mn;
    }
  __syncthreads();
  if (t < 128) {
    const float m = fminf(rmkt[t * 2], rmkt[t * 2 + 1]);
    bmin[t] = m;
    atomicMin(&gmin[r0 + t], __float_as_int(m));  // bits monotone for s>0
  }
  __syncthreads();
  // epilogue pass 2: append candidates within DELTA of chunk-local min
#pragma unroll
  for (int tr = 0; tr < 4; ++tr)
#pragma unroll
    for (int rg = 0; rg < 4; ++rg) {
      const int rloc = wr * 64 + tr * 16 + quad * 4 + rg;
      const float av = a_l[rloc];
      const float lim = bmin[rloc] + DELTA;
#pragma unroll
      for (int tc = 0; tc < 4; ++tc) {
        const int cloc = wc * 64 + tc * 16 + l15;
        const float s = av + fmaf(-2.0f, acc[tr][tc][rg], c_l[cloc]);
        if (s <= lim) {
          const int pos = atomicAdd(&gcnt[r0 + rloc], 1);
          if (pos < NSLOT)
            gcand[(size_t)(r0 + rloc) * NSLOT + pos] =
                make_float2(s, __int_as_float(k0 + cloc));
        }
      }
    }
}

// ---------------------------------------------------------------------------
// k_finish: filter stored candidates by final gmin+DELTA (~1.3 survive/row),
// exact fp32 rescore (r3's proven chain), strict < + lowest-k tie-break.
// ---------------------------------------------------------------------------
__global__ __launch_bounds__(256) void k_finish(
    const float* __restrict__ z, const float* __restrict__ emb,
    const float* __restrict__ cws, const float* __restrict__ aws,
    const int* __restrict__ gmin, const int* __restrict__ gcnt,
    const float2* __restrict__ gcand, int* __restrict__ idxws,
    float* __restrict__ out) {
  const int r = (blockIdx.x << 8) + threadIdx.x;
  const float lim = __int_as_float(gmin[r]) + DELTA;
  int m = gcnt[r];
  if (m > NSLOT) m = NSLOT;
  const int n = r >> 10, hw = r & 1023;
  const float* zp = z + (size_t)n * 262144 + hw;
  const float a = aws[r];
  float bestv = FLT_MAX;
  int besti = 0x7fffffff;
  for (int ci = 0; ci < m; ++ci) {
    const float2 p = gcand[(size_t)r * NSLOT + ci];
    if (p.x > lim) continue;
    const int k = __float_as_int(p.y);
    const float* ep = emb + (size_t)k * 256;
    float dot = 0.0f;
#pragma unroll 8
    for (int d = 0; d < 256; ++d) dot = fmaf(zp[(size_t)d * 1024], ep[d], dot);
    float s = fmaf(-2.0f, dot, a);  // fl(a - 2*dot)
    s = s + cws[k];                 // fl(s + c)
    if (s < bestv || (s == bestv && k < besti)) {
      bestv = s;
      besti = k;
    }
  }
  idxws[r] = besti;
  out[OUT_IDX_OFF + r] = (float)besti;
}

// ---------------------------------------------------------------------------
// k_out: z_q gather + loss (proven, unchanged). Overwrites all d_out scratch.
// ---------------------------------------------------------------------------
__global__ __launch_bounds__(256) void k_out(const float* __restrict__ z,
                                             const float* __restrict__ emb,
                                             const int* __restrict__ idxws,
                                             float* __restrict__ out) {
  __shared__ float zq[32][257];
  __shared__ int sidx[32];
  __shared__ float red[256];
  const int t = threadIdx.x;
  const int p0 = blockIdx.x << 5;
  const int n = p0 >> 10, hw0 = p0 & 1023;
  if (t < 32) sidx[t] = idxws[p0 + t];
  __syncthreads();
#pragma unroll
  for (int it = 0; it < 8; ++it) {
    const int i = t + (it << 8);
    const int p = i >> 6;
    const int q = (i & 63) << 2;
    const float4 v = *(const float4*)&emb[(size_t)sidx[p] * 256 + q];
    zq[p][q] = v.x;
    zq[p][q + 1] = v.y;
    zq[p][q + 2] = v.z;
    zq[p][q + 3] = v.w;
  }
  __syncthreads();
  const int p = t & 31, d0 = t >> 5;
  const float* zb = z + (size_t)n * 262144 + hw0 + p;
  float* ob = out + (size_t)n * 262144 + hw0 + p;
  float lacc = 0.0f;
#pragma unroll
  for (int dd = 0; dd < 32; ++dd) {
    const int d = (dd << 3) + d0;
    const float v = zq[p][d];
    const float zv = zb[(size_t)d * 1024];
    ob[(size_t)d * 1024] = v;
    const float df = zv - v;
    lacc = fmaf(df, df, lacc);
  }
  red[t] = lacc;
  __syncthreads();
  for (int s = 128; s > 0; s >>= 1) {
    if (t < s) red[t] += red[t + s];
    __syncthreads();
  }
  if (t == 0) atomicAdd(&out[OUT_LOSS_OFF], red[0] * (1.02f / 16777216.0f));
}

// ---------------------------------------------------------------------------
extern "C" void kernel_launch(void* const* d_in, const int* in_sizes, int n_in,
                              void* d_out, int out_size, void* d_ws,
                              size_t ws_size, hipStream_t stream) {
  const float* z = (const float*)d_in[0];
  const float* emb = (const float*)d_in[1];
  float* out = (float*)d_out;

  // ws layout: E2 bf16 [1024*256] | cws [1024] | aws [65536] | idx [65536]
  unsigned short* E2 = (unsigned short*)d_ws;
  float* cws = (float*)(E2 + 262144);
  float* aws = cws + 1024;
  int* idxws = (int*)(aws + 65536);
  // scratch in d_out's z_q region (k_out overwrites it last):
  unsigned short* A2 = (unsigned short*)d_out;
  float2* gcand = (float2*)(out + CAND_OFF);
  int* gmin = (int*)(out + GMIN_OFF);
  int* gcnt = (int*)(out + GCNT_OFF);

  hipMemsetAsync((char*)d_out + (size_t)OUT_LOSS_OFF * 4, 0, 4, stream);
  hipMemsetAsync(gmin, 0x7f, 65536 * 4, stream);  // 0x7f7f7f7f ~ +inf
  hipMemsetAsync(gcnt, 0, 65536 * 4, stream);

  k_prep<<<dim3(1024), dim3(256), 0, stream>>>(emb, E2, cws);
  k_cvt<<<dim3(2048), dim3(256), 0, stream>>>(z, A2);
  k_a<<<dim3(512), dim3(256), 0, stream>>>(z, aws);
  k_gemm2<<<dim3(4096), dim3(256), 0, stream>>>(A2, E2, cws, aws, gmin, gcnt,
                                                gcand);
  k_finish<<<dim3(256), dim3(256), 0, stream>>>(z, emb, cws, aws, gmin, gcnt,
                                                gcand, idxws, out);
  k_out<<<dim3(2048), dim3(256), 0, stream>>>(z, emb, idxws, out);
}

// Round 5
// 337.037 us; speedup vs baseline: 1.7171x; 1.7171x over previous
//
#include <hip/hip_runtime.h>
#include <hip/hip_bf16.h>
#include <float.h>

// z: (64, 256, 32, 32) fp32 ; emb: (1024, 256) fp32
// M = 65536 pixels, D = 256, K = 1024 codes
// out: [z_q (16777216 f)] [indices as float (65536)] [vq_loss (1)]
#define OUT_IDX_OFF 16777216
#define OUT_LOSS_OFF 16842752
// scratch inside d_out's z_q region (overwritten by k_out at the end):
// A2 bf16: floats [0, 8388608)
// cand pairs (s,k) float2: floats [8388608, 12582912)  65536 rows x 32 slots
// gmin (int-punned f32):   floats [12582912, 13107200)
// gcnt (int):              floats [13107200, 13631488)
#define CAND_OFF 8388608
#define GMIN_OFF 12582912
#define GCNT_OFF 13107200
#define NSLOT 32
#define DELTA 2.0e-3f

typedef __attribute__((ext_vector_type(8))) short short8;
typedef __attribute__((ext_vector_type(4))) float f32x4;

static __device__ __forceinline__ unsigned short f2bf(float f) {
  union { __hip_bfloat16 h; unsigned short u; } cv;
  cv.h = __float2bfloat16(f);
  return cv.u;
}

// ---------------------------------------------------------------------------
// P1: emb -> E2 bf16 [1024 codes][256 d] + exact cws (proven r1-r4).
// ---------------------------------------------------------------------------
__global__ __launch_bounds__(256) void k_prep(const float* __restrict__ emb,
                                              unsigned short* __restrict__ E2,
                                              float* __restrict__ cws) {
  const int k = blockIdx.x, d = threadIdx.x;
  const float v = emb[k * 256 + d];
  __shared__ float red[256];
  __shared__ unsigned short row[256];
  row[d] = f2bf(v);
  red[d] = v * v;
  __syncthreads();
  for (int s = 128; s > 0; s >>= 1) {
    if (d < s) red[d] += red[d + s];
    __syncthreads();
  }
  if (d == 0) cws[k] = red[0];
  if (d < 32) ((short8*)&E2[k * 256])[d] = ((short8*)row)[d];
}

// ---------------------------------------------------------------------------
// P2 v2: z (NCHW) -> A2 bf16 [pixel][256]. 64px x 64d tiles; float4 loads
// fully coalesced along hw; LDS transpose (2-way bank aliasing only = free);
// short8 stores. Replaces r3/r4's ~93us latency-bound strided version.
// ---------------------------------------------------------------------------
__global__ __launch_bounds__(256) void k_cvt2(const float* __restrict__ z,
                                              unsigned short* __restrict__ A2) {
  __shared__ float tile[64][65];
  const int t = threadIdx.x;
  const int pt = blockIdx.x >> 2, dt = blockIdx.x & 3;
  const int p0 = pt << 6, d0 = dt << 6;
  const int n = p0 >> 10, hw0 = p0 & 1023;
  const float* zb = z + (size_t)n * 262144 + (size_t)d0 * 1024 + hw0;
  const int hwl = (t & 15) << 2;
#pragma unroll
  for (int i = 0; i < 4; ++i) {
    const int dl = (t >> 4) + i * 16;
    const float4 v = *(const float4*)&zb[(size_t)dl * 1024 + hwl];
    tile[hwl + 0][dl] = v.x;
    tile[hwl + 1][dl] = v.y;
    tile[hwl + 2][dl] = v.z;
    tile[hwl + 3][dl] = v.w;
  }
  __syncthreads();
  const int pl = t >> 2, c = t & 3;
  unsigned short* dst = &A2[(size_t)(p0 + pl) * 256 + d0];
#pragma unroll
  for (int h = 0; h < 2; ++h) {
    const int ch = c + h * 4;
    unsigned short tmp[8];
#pragma unroll
    for (int j = 0; j < 8; ++j) tmp[j] = f2bf(tile[pl][ch * 8 + j]);
    *(short8*)&dst[ch * 8] = *(short8*)tmp;
  }
}

// ---------------------------------------------------------------------------
// k_a: exact numpy-pairwise ||x||^2 (proven, unchanged).
// ---------------------------------------------------------------------------
__global__ __launch_bounds__(256) void k_a(const float* __restrict__ z,
                                           float* __restrict__ aws) {
#pragma clang fp contract(off)
  const int t = threadIdx.x;
  const int r = (blockIdx.x << 7) + (t & 127);
  const int h = t >> 7;
  const int n = r >> 10;
  const int hw = r & 1023;
  const float* zp = z + (size_t)n * 262144 + hw + (size_t)h * 131072;
  float acc[8];
#pragma unroll
  for (int j = 0; j < 8; ++j) {
    const float x = zp[(size_t)j * 1024];
    acc[j] = x * x;
  }
  for (int g = 1; g < 16; ++g) {
#pragma unroll
    for (int j = 0; j < 8; ++j) {
      const float x = zp[(size_t)(g * 8 + j) * 1024];
      const float p = x * x;
      acc[j] = acc[j] + p;
    }
  }
  const float s = ((acc[0] + acc[1]) + (acc[2] + acc[3])) +
                  ((acc[4] + acc[5]) + (acc[6] + acc[7]));
  __shared__ float red[256];
  red[t] = s;
  __syncthreads();
  if (t < 128) aws[(blockIdx.x << 7) + t] = red[t] + red[t + 128];
}

// ---------------------------------------------------------------------------
// k_gemm2: MFMA prefilter (structure proven r4: XOR-swizzle -> 0 bank
// conflicts). Changes: __launch_bounds__(256,3) (cap 170 VGPR, 3 blocks/CU;
// r4's (256,1) left occupancy to chance) and tightened candidate appends:
// bmin = min(chunk_min, gmin_so_far) -- winner still provably appended since
// s_w <= gmin_final + DELTA <= min(chunkmin, gmin_now) + DELTA.
// ---------------------------------------------------------------------------
__global__ __launch_bounds__(256, 3) void k_gemm2(
    const unsigned short* __restrict__ A2, const unsigned short* __restrict__ E2,
    const float* __restrict__ cws, const float* __restrict__ aws,
    int* __restrict__ gmin, int* __restrict__ gcnt,
    float2* __restrict__ gcand) {
  __shared__ __align__(16) unsigned short As[128 * 64];
  __shared__ __align__(16) unsigned short Bs[128 * 64];
  __shared__ float a_l[128], c_l[128], rmkt[256], bmin[128];

  const int t = threadIdx.x;
  const int lane = t & 63, wave = t >> 6;
  const int wr = wave >> 1, wc = wave & 1;
  const int quad = lane >> 4, l15 = lane & 15;
  const int rb = blockIdx.x >> 3, ck = blockIdx.x & 7;
  const int r0 = rb << 7, k0 = ck << 7;

  if (t < 128) {
    a_l[t] = aws[r0 + t];
    c_l[t] = cws[k0 + t];
  }

  const short8* gA8 = (const short8*)A2;
  const short8* gE8 = (const short8*)E2;
  const int srow = t >> 3;
  const int sch = t & 7;
  const int swst = (sch ^ (srow & 7)) << 3;
  const int swa = l15 & 7;

  f32x4 acc[4][4];
#pragma unroll
  for (int a = 0; a < 4; ++a)
#pragma unroll
    for (int b = 0; b < 4; ++b) acc[a][b] = (f32x4)(0.0f);

  for (int kt = 0; kt < 4; ++kt) {
    if (kt) __syncthreads();
    short8 va[4], vb[4];
#pragma unroll
    for (int s = 0; s < 4; ++s) {
      const int row = s * 32 + srow;
      va[s] = gA8[(size_t)(r0 + row) * 32 + kt * 8 + sch];
      vb[s] = gE8[(size_t)(k0 + row) * 32 + kt * 8 + sch];
    }
#pragma unroll
    for (int s = 0; s < 4; ++s) {
      const int row = s * 32 + srow;
      *(short8*)&As[row * 64 + swst] = va[s];
      *(short8*)&Bs[row * 64 + swst] = vb[s];
    }
    __syncthreads();
#pragma unroll
    for (int ks = 0; ks < 2; ++ks) {
      short8 af[4], bf[4];
#pragma unroll
      for (int tr = 0; tr < 4; ++tr)
        af[tr] = *(const short8*)&As[(wr * 64 + tr * 16 + l15) * 64 +
                                     (((ks * 4 + quad) ^ swa) << 3)];
#pragma unroll
      for (int tc = 0; tc < 4; ++tc)
        bf[tc] = *(const short8*)&Bs[(wc * 64 + tc * 16 + l15) * 64 +
                                     (((ks * 4 + quad) ^ swa) << 3)];
#pragma unroll
      for (int tr = 0; tr < 4; ++tr)
#pragma unroll
        for (int tc = 0; tc < 4; ++tc)
          acc[tr][tc] = __builtin_amdgcn_mfma_f32_16x16x32_bf16(
              af[tr], bf[tc], acc[tr][tc], 0, 0, 0);
    }
  }

  // epilogue pass 1: chunk-local per-row min
#pragma unroll
  for (int tr = 0; tr < 4; ++tr)
#pragma unroll
    for (int rg = 0; rg < 4; ++rg) {
      const int rloc = wr * 64 + tr * 16 + quad * 4 + rg;
      const float av = a_l[rloc];
      float mn = FLT_MAX;
#pragma unroll
      for (int tc = 0; tc < 4; ++tc) {
        const int cloc = wc * 64 + tc * 16 + l15;
        const float s = av + fmaf(-2.0f, acc[tr][tc][rg], c_l[cloc]);
        mn = fminf(mn, s);
      }
      mn = fminf(mn, __shfl_xor(mn, 1));
      mn = fminf(mn, __shfl_xor(mn, 2));
      mn = fminf(mn, __shfl_xor(mn, 4));
      mn = fminf(mn, __shfl_xor(mn, 8));
      if (l15 == 0) rmkt[rloc * 2 + wc] = mn;
    }
  __syncthreads();
  if (t < 128) {
    const float m = fminf(rmkt[t * 2], rmkt[t * 2 + 1]);
    const int old = atomicMin(&gmin[r0 + t], __float_as_int(m));
    bmin[t] = fminf(m, __int_as_float(old));  // bits monotone for s>0
  }
  __syncthreads();
  // epilogue pass 2: append candidates within DELTA of tightened min
#pragma unroll
  for (int tr = 0; tr < 4; ++tr)
#pragma unroll
    for (int rg = 0; rg < 4; ++rg) {
      const int rloc = wr * 64 + tr * 16 + quad * 4 + rg;
      const float av = a_l[rloc];
      const float lim = bmin[rloc] + DELTA;
#pragma unroll
      for (int tc = 0; tc < 4; ++tc) {
        const int cloc = wc * 64 + tc * 16 + l15;
        const float s = av + fmaf(-2.0f, acc[tr][tc][rg], c_l[cloc]);
        if (s <= lim) {
          const int pos = atomicAdd(&gcnt[r0 + rloc], 1);
          if (pos < NSLOT)
            gcand[(size_t)(r0 + rloc) * NSLOT + pos] =
                make_float2(s, __int_as_float(k0 + cloc));
        }
      }
    }
}

// ---------------------------------------------------------------------------
// k_finish v2: 4 lanes per row (grid x4 -> ~16 waves/CU), candidates strided
// across the quad, exact rescore chain UNCHANGED (bit-identical scores ->
// identical indices), quad shuffle-reduce with strict-< + lowest-k.
// Also accumulates vq_loss: winner's s IS ||z-e||^2 for that row.
// ---------------------------------------------------------------------------
__global__ __launch_bounds__(256) void k_finish(
    const float* __restrict__ z, const float* __restrict__ emb,
    const float* __restrict__ cws, const float* __restrict__ aws,
    const int* __restrict__ gmin, const int* __restrict__ gcnt,
    const float2* __restrict__ gcand, int* __restrict__ idxws,
    float* __restrict__ out) {
  const int tid = (blockIdx.x << 8) + threadIdx.x;
  const int r = tid >> 2, sub = tid & 3;
  const float lim = __int_as_float(gmin[r]) + DELTA;
  int m = gcnt[r];
  if (m > NSLOT) m = NSLOT;
  const int n = r >> 10, hw = r & 1023;
  const float* zp = z + (size_t)n * 262144 + hw;
  const float a = aws[r];
  float bestv = FLT_MAX;
  int besti = 0x7fffffff;
  for (int ci = sub; ci < m; ci += 4) {
    const float2 p = gcand[(size_t)r * NSLOT + ci];
    if (p.x > lim) continue;
    const int k = __float_as_int(p.y);
    const float* ep = emb + (size_t)k * 256;
    float dot = 0.0f;
#pragma unroll 8
    for (int d = 0; d < 256; ++d) dot = fmaf(zp[(size_t)d * 1024], ep[d], dot);
    float s = fmaf(-2.0f, dot, a);  // fl(a - 2*dot)
    s = s + cws[k];                 // fl(s + c)
    if (s < bestv || (s == bestv && k < besti)) {
      bestv = s;
      besti = k;
    }
  }
#pragma unroll
  for (int off = 1; off < 4; off <<= 1) {
    const float ov = __shfl_xor(bestv, off);
    const int oi = __shfl_xor(besti, off);
    if (ov < bestv || (ov == bestv && oi < besti)) {
      bestv = ov;
      besti = oi;
    }
  }
  if (sub == 0) {
    idxws[r] = besti;
    out[OUT_IDX_OFF + r] = (float)besti;
  }
  float c = (sub == 0) ? bestv : 0.0f;
#pragma unroll
  for (int off = 1; off < 64; off <<= 1) c += __shfl_xor(c, off);
  if ((threadIdx.x & 63) == 0)
    atomicAdd(&out[OUT_LOSS_OFF], c * (1.02f / 16777216.0f));
}

// ---------------------------------------------------------------------------
// k_out2: pure z_q gather-write (loss moved to k_finish; no z read).
// Overwrites all d_out scratch regions.
// ---------------------------------------------------------------------------
__global__ __launch_bounds__(256) void k_out2(const float* __restrict__ emb,
                                              const int* __restrict__ idxws,
                                              float* __restrict__ out) {
  __shared__ float zq[32][257];
  __shared__ int sidx[32];
  const int t = threadIdx.x;
  const int p0 = blockIdx.x << 5;
  const int n = p0 >> 10, hw0 = p0 & 1023;
  if (t < 32) sidx[t] = idxws[p0 + t];
  __syncthreads();
#pragma unroll
  for (int it = 0; it < 8; ++it) {
    const int i = t + (it << 8);
    const int p = i >> 6;
    const int q = (i & 63) << 2;
    const float4 v = *(const float4*)&emb[(size_t)sidx[p] * 256 + q];
    zq[p][q] = v.x;
    zq[p][q + 1] = v.y;
    zq[p][q + 2] = v.z;
    zq[p][q + 3] = v.w;
  }
  __syncthreads();
  const int p = t & 31, d0 = t >> 5;
  float* ob = out + (size_t)n * 262144 + hw0 + p;
#pragma unroll
  for (int dd = 0; dd < 32; ++dd) {
    const int d = (dd << 3) + d0;
    ob[(size_t)d * 1024] = zq[p][d];
  }
}

// ---------------------------------------------------------------------------
extern "C" void kernel_launch(void* const* d_in, const int* in_sizes, int n_in,
                              void* d_out, int out_size, void* d_ws,
                              size_t ws_size, hipStream_t stream) {
  const float* z = (const float*)d_in[0];
  const float* emb = (const float*)d_in[1];
  float* out = (float*)d_out;

  // ws layout: E2 bf16 [1024*256] | cws [1024] | aws [65536] | idx [65536]
  unsigned short* E2 = (unsigned short*)d_ws;
  float* cws = (float*)(E2 + 262144);
  float* aws = cws + 1024;
  int* idxws = (int*)(aws + 65536);
  // scratch in d_out's z_q region (k_out2 overwrites it last):
  unsigned short* A2 = (unsigned short*)d_out;
  float2* gcand = (float2*)(out + CAND_OFF);
  int* gmin = (int*)(out + GMIN_OFF);
  int* gcnt = (int*)(out + GCNT_OFF);

  hipMemsetAsync((char*)d_out + (size_t)OUT_LOSS_OFF * 4, 0, 4, stream);
  hipMemsetAsync(gmin, 0x7f, 65536 * 4, stream);  // 0x7f7f7f7f ~ +inf
  hipMemsetAsync(gcnt, 0, 65536 * 4, stream);

  k_prep<<<dim3(1024), dim3(256), 0, stream>>>(emb, E2, cws);
  k_cvt2<<<dim3(4096), dim3(256), 0, stream>>>(z, A2);
  k_a<<<dim3(512), dim3(256), 0, stream>>>(z, aws);
  k_gemm2<<<dim3(4096), dim3(256), 0, stream>>>(A2, E2, cws, aws, gmin, gcnt,
                                                gcand);
  k_finish<<<dim3(1024), dim3(256), 0, stream>>>(z, emb, cws, aws, gmin, gcnt,
                                                 gcand, idxws, out);
  k_out2<<<dim3(2048), dim3(256), 0, stream>>>(emb, idxws, out);
}